// Round 3
// baseline (817.744 us; speedup 1.0000x reference)
//
#include <hip/hip_runtime.h>

// Problem constants (from reference)
constexpr int KDIM  = 128;
constexpr int NEXER = 16384;
constexpr int NNODE = KDIM + NEXER;   // 16512
constexpr int NEDGE = 400000;
constexpr int NBATCH = 4096;
constexpr int NHIST = NBATCH * 50;    // 204800

// CSR build partitioning: C edge-chunks x R node-ranges (LDS hist = NNODE/R ints)
constexpr int NCHUNK = 8;
constexpr int CHSZ   = NEDGE / NCHUNK;  // 50000
constexpr int RHALF  = NNODE / 2;       // 8256 -> 33 KB LDS

typedef __attribute__((ext_vector_type(8))) short bf16x8;
typedef __attribute__((ext_vector_type(4))) float f32x4;

__device__ __forceinline__ float sigmoidf(float x) {
    return 1.0f / (1.0f + __expf(-x));
}

// round-to-nearest-even fp32 -> bf16 (as ushort)
__device__ __forceinline__ ushort f2bf(float f) {
    uint x = __float_as_uint(f);
    uint r = (x + 0x7FFFu + ((x >> 16) & 1u)) >> 16;
    return (ushort)r;
}

// ---------------------------------------------------------------- prep: entity->bf16, full_acc=entity
__global__ __launch_bounds__(256) void prep_emb_kernel(
    const float* __restrict__ entity, ushort* __restrict__ h_bf,
    float* __restrict__ full_acc)
{
    int idx = blockIdx.x * 256 + threadIdx.x;  // over N*K/2
    if (idx >= NNODE * KDIM / 2) return;
    float2 v = ((const float2*)entity)[idx];
    ((float2*)full_acc)[idx] = v;
    ((uint*)h_bf)[idx] = (uint)f2bf(v.x) | ((uint)f2bf(v.y) << 16);
}

// ---------------------------------------------------------------- prep: W (3,4,K,K) -> bf16 transposed Wt[g,l][n][k]
__global__ __launch_bounds__(256) void prep_w_kernel(
    const float* __restrict__ W, ushort* __restrict__ Wt)
{
    __shared__ float tile[32][33];
    int gl = blockIdx.y;               // 0..11
    int tk = blockIdx.x >> 2, tn = blockIdx.x & 3;
    int k0 = tk * 32, n0 = tn * 32;
    int tx = threadIdx.x & 31, ty = threadIdx.x >> 5;  // ty 0..7
    const float* src = W + ((size_t)gl << 14);
    #pragma unroll
    for (int i = 0; i < 4; ++i) {
        int k = ty * 4 + i;
        tile[k][tx] = src[(k0 + k) * 128 + n0 + tx];
    }
    __syncthreads();
    ushort* dst = Wt + ((size_t)gl << 14);
    #pragma unroll
    for (int i = 0; i < 4; ++i) {
        int n = ty * 4 + i;
        dst[(n0 + n) * 128 + k0 + tx] = f2bf(tile[tx][n]);
    }
}

// ---------------------------------------------------------------- partial degree hist (no global atomics)
// grid: (NCHUNK, 2, 6)  z = g*2+side (side 0=src,1=dst)
__global__ __launch_bounds__(256) void count_part_kernel(
    const int* __restrict__ s0, const int* __restrict__ d0,
    const int* __restrict__ s1, const int* __restrict__ d1,
    const int* __restrict__ s2, const int* __restrict__ d2,
    int* __restrict__ partial)   // [6][NCHUNK][NNODE]
{
    __shared__ int hist[RHALF];
    int c = blockIdx.x, r = blockIdx.y, gs = blockIdx.z;
    const int* arr = (gs == 0) ? s0 : (gs == 1) ? d0 : (gs == 2) ? s1
                   : (gs == 3) ? d1 : (gs == 4) ? s2 : d2;
    for (int i = threadIdx.x; i < RHALF; i += 256) hist[i] = 0;
    __syncthreads();
    int base = r * RHALF;
    const int* p = arr + c * CHSZ;
    for (int i = threadIdx.x; i < CHSZ; i += 256) {
        int v = p[i] - base;
        if ((unsigned)v < (unsigned)RHALF) atomicAdd(&hist[v], 1);
    }
    __syncthreads();
    int* outp = partial + ((size_t)gs * NCHUNK + c) * NNODE + base;
    for (int i = threadIdx.x; i < RHALF; i += 256) outp[i] = hist[i];
}

// ---------------------------------------------------------------- sum partials -> cnt[6][NNODE]
__global__ __launch_bounds__(256) void sum_kernel(
    const int* __restrict__ partial, int* __restrict__ cnt)
{
    int idx = blockIdx.x * 256 + threadIdx.x;
    if (idx >= 6 * NNODE) return;
    int gs = idx / NNODE, node = idx - gs * NNODE;
    const int* pp = partial + (size_t)gs * NCHUNK * NNODE + node;
    int s = 0;
    #pragma unroll
    for (int c = 0; c < NCHUNK; ++c) s += pp[c * NNODE];
    cnt[idx] = s;
}

// ---------------------------------------------------------------- row_ptr scan (reads cnt dst-planes)
__global__ __launch_bounds__(256) void scan_kernel(
    const int* __restrict__ cnt, int* __restrict__ rp)
{
    int g = blockIdx.x;
    const int* c = cnt + (g * 2 + 1) * NNODE;   // dst side
    int* r = rp + g * (NNODE + 1);
    __shared__ int part[256];
    int t = threadIdx.x;
    constexpr int CH = (NNODE + 255) / 256;  // 65
    int lo = t * CH;
    int hi = lo + CH; if (hi > NNODE) hi = NNODE;
    int s = 0;
    for (int i = lo; i < hi; ++i) s += c[i];
    part[t] = s;
    __syncthreads();
    for (int off = 1; off < 256; off <<= 1) {
        int v = part[t];
        if (t >= off) v += part[t - off];
        __syncthreads();
        part[t] = v;
        __syncthreads();
    }
    int run = (t == 0) ? 0 : part[t - 1];
    for (int i = lo; i < hi; ++i) { r[i] = run; run += c[i]; }
    if (t == 255) r[NNODE] = part[255];
}

// ---------------------------------------------------------------- chunk_base[g][c][node] = rp + excl-scan of dst partials over c
__global__ __launch_bounds__(256) void base_kernel(
    const int* __restrict__ partial, const int* __restrict__ rp,
    int* __restrict__ chunk_base)
{
    int idx = blockIdx.x * 256 + threadIdx.x;
    if (idx >= 3 * NNODE) return;
    int g = idx / NNODE, node = idx - g * NNODE;
    int running = rp[g * (NNODE + 1) + node];
    const int* pp = partial + (size_t)(g * 2 + 1) * NCHUNK * NNODE + node;
    int* ob = chunk_base + (size_t)g * NCHUNK * NNODE + node;
    #pragma unroll
    for (int c = 0; c < NCHUNK; ++c) { ob[c * NNODE] = running; running += pp[c * NNODE]; }
}

// ---------------------------------------------------------------- CSR fill via LDS ranks (no global atomics)
// grid: (NCHUNK, 2, 3)
__global__ __launch_bounds__(256) void fill_part_kernel(
    const int* __restrict__ s0, const int* __restrict__ d0,
    const int* __restrict__ s1, const int* __restrict__ d1,
    const int* __restrict__ s2, const int* __restrict__ d2,
    const int* __restrict__ cnt, const int* __restrict__ chunk_base,
    int* __restrict__ csr_src, float* __restrict__ csr_w)
{
    __shared__ int fch[RHALF];
    int c = blockIdx.x, r = blockIdx.y, g = blockIdx.z;
    const int* s = (g == 0) ? s0 : (g == 1) ? s1 : s2;
    const int* d = (g == 0) ? d0 : (g == 1) ? d1 : d2;
    for (int i = threadIdx.x; i < RHALF; i += 256) fch[i] = 0;
    __syncthreads();
    int base = r * RHALF;
    const int* cs = cnt + (g * 2 + 0) * NNODE;
    const int* cd = cnt + (g * 2 + 1) * NNODE;
    const int* cb = chunk_base + ((size_t)g * NCHUNK + c) * NNODE;
    int* osrc = csr_src + (size_t)g * NEDGE;
    float* ow = csr_w + (size_t)g * NEDGE;
    const int* sp = s + c * CHSZ;
    const int* dp = d + c * CHSZ;
    for (int i = threadIdx.x; i < CHSZ; i += 256) {
        int sv = sp[i], dv = dp[i];
        int dr = dv - base;
        if ((unsigned)dr < (unsigned)RHALF) {
            int rank = atomicAdd(&fch[dr], 1);
            int pos = cb[dv] + rank;
            int a = cs[sv]; if (a < 1) a = 1;
            int b = cd[dv]; if (b < 1) b = 1;
            osrc[pos] = sv;
            ow[pos] = rsqrtf((float)a * (float)b);
        }
    }
}

// ---------------------------------------------------------------- CSR gather (bf16 h): agg_g[d] = sum_e w*h[src]
__global__ __launch_bounds__(256) void gather_kernel(
    const ushort* __restrict__ h_bf, const int* __restrict__ csr_src,
    const float* __restrict__ csr_w, const int* __restrict__ rp,
    ushort* __restrict__ agg)
{
    int wave = threadIdx.x >> 6, lane = threadIdx.x & 63;
    int row = blockIdx.x * 4 + wave;
    if (row >= NNODE) return;
    const uint* hb = (const uint*)h_bf;   // one uint = 2 bf16 cols
    for (int g = 0; g < 3; ++g) {
        int js = rp[g * (NNODE + 1) + row], je = rp[g * (NNODE + 1) + row + 1];
        const int* srcs = csr_src + (size_t)g * NEDGE;
        const float* ws = csr_w + (size_t)g * NEDGE;
        float ax = 0.f, ay = 0.f;
        int j = js;
        for (; j + 1 < je; j += 2) {
            int u0 = srcs[j], u1 = srcs[j + 1];
            float w0 = ws[j], w1 = ws[j + 1];
            uint p0 = hb[(size_t)u0 * 64 + lane];
            uint p1 = hb[(size_t)u1 * 64 + lane];
            ax += w0 * __uint_as_float(p0 << 16);
            ay += w0 * __uint_as_float(p0 & 0xFFFF0000u);
            ax += w1 * __uint_as_float(p1 << 16);
            ay += w1 * __uint_as_float(p1 & 0xFFFF0000u);
        }
        if (j < je) {
            int u = srcs[j]; float w = ws[j];
            uint p = hb[(size_t)u * 64 + lane];
            ax += w * __uint_as_float(p << 16);
            ay += w * __uint_as_float(p & 0xFFFF0000u);
        }
        uint outp = (uint)f2bf(ax) | ((uint)f2bf(ay) << 16);
        ((uint*)agg)[((size_t)g * NNODE + row) * 64 + lane] = outp;
    }
}

// ---------------------------------------------------------------- MFMA GEMM: h_next = sum_g agg_g @ W[g,l] + bsum
__global__ __launch_bounds__(256) void gemm_kernel(
    const ushort* __restrict__ agg, const ushort* __restrict__ Wt,
    const float* __restrict__ gcnB, int layer,
    ushort* __restrict__ h_bf, float* __restrict__ full_acc,
    float* __restrict__ disc_acc)
{
    __shared__ ushort Wlds[128 * 136];   // pad 136: 2-way max bank aliasing (free)
    __shared__ float bsum[128];
    int t = threadIdx.x;
    int wave = t >> 6, lane = t & 63;
    int R0 = blockIdx.x * 64;
    if (t < 128)
        bsum[t] = gcnB[(0 * 4 + layer) * 128 + t] + gcnB[(1 * 4 + layer) * 128 + t]
                + gcnB[(2 * 4 + layer) * 128 + t];
    int m = lane & 15, q = lane >> 4;
    int arow = R0 + wave * 16 + m;
    f32x4 acc[8];
    #pragma unroll
    for (int n = 0; n < 8; ++n) acc[n] = (f32x4){0.f, 0.f, 0.f, 0.f};
    for (int g = 0; g < 3; ++g) {
        __syncthreads();
        const ushort* src = Wt + ((size_t)(g * 4 + layer) << 14);
        for (int i = t; i < 2048; i += 256) {          // 128 rows x 16 uint4
            int row = i >> 4, c = i & 15;
            *(uint4*)&Wlds[row * 136 + c * 8] = *(const uint4*)(src + row * 128 + c * 8);
        }
        __syncthreads();
        const ushort* ap = agg + ((size_t)g * NNODE + arow) * 128 + q * 8;
        bf16x8 af[4];
        #pragma unroll
        for (int k = 0; k < 4; ++k) af[k] = *(const bf16x8*)(ap + k * 32);
        #pragma unroll
        for (int n = 0; n < 8; ++n) {
            const ushort* bp = &Wlds[(n * 16 + m) * 136 + q * 8];
            #pragma unroll
            for (int k = 0; k < 4; ++k) {
                bf16x8 bfr = *(const bf16x8*)(bp + k * 32);
                acc[n] = __builtin_amdgcn_mfma_f32_16x16x32_bf16(af[k], bfr, acc[n], 0, 0, 0);
            }
        }
    }
    __syncthreads();
    float* stage = (float*)Wlds;       // reuse LDS (34816 B >= 32768 B)
    #pragma unroll
    for (int n = 0; n < 8; ++n) {
        #pragma unroll
        for (int r = 0; r < 4; ++r)
            stage[(wave * 16 + q * 4 + r) * 128 + n * 16 + m] = acc[n][r];
    }
    __syncthreads();
    for (int idx = t; idx < 64 * 128; idx += 256) {
        int row = idx >> 7, col = idx & 127;
        int gr = R0 + row;
        float v = stage[idx] + bsum[col];
        size_t o = (size_t)gr * 128 + col;
        full_acc[o] += v;
        h_bf[o] = f2bf(v);
        if (gr >= KDIM) {
            size_t od = (size_t)(gr - KDIM) * 128 + col;
            if (layer == 2) disc_acc[od] = v;
            else if (layer == 3) disc_acc[od] += v;
        }
    }
}

// ---------------------------------------------------------------- full/=5, disc/=2
__global__ __launch_bounds__(256) void scale_kernel(
    float* __restrict__ full_acc, float* __restrict__ disc_acc)
{
    constexpr int NK4 = NNODE * KDIM / 4;
    constexpr int DK4 = NEXER * KDIM / 4;
    int idx = blockIdx.x * blockDim.x + threadIdx.x;
    if (idx < NK4) {
        float4 v = ((float4*)full_acc)[idx];
        v.x *= 0.2f; v.y *= 0.2f; v.z *= 0.2f; v.w *= 0.2f;
        ((float4*)full_acc)[idx] = v;
    } else if (idx < NK4 + DK4) {
        int i = idx - NK4;
        float4 v = ((float4*)disc_acc)[i];
        v.x *= 0.5f; v.y *= 0.5f; v.z *= 0.5f; v.w *= 0.5f;
        ((float4*)disc_acc)[i] = v;
    }
}

// ---------------------------------------------------------------- segment starts (segids sorted)
__global__ __launch_bounds__(256) void starts_kernel(
    const int* __restrict__ segids, int* __restrict__ starts)
{
    int i = blockIdx.x * blockDim.x + threadIdx.x;
    if (i > NBATCH) return;
    int lo = 0, hi = NHIST;
    while (lo < hi) {
        int m = (lo + hi) >> 1;
        if (segids[m] < i) lo = m + 1; else hi = m;
    }
    starts[i] = lo;
}

// ---------------------------------------------------------------- stu pooling: wave per batch row
__global__ __launch_bounds__(256) void stu_kernel(
    const float* __restrict__ disc, const int* __restrict__ hist,
    const int* __restrict__ starts, float* __restrict__ stu)
{
    int wave = threadIdx.x >> 6, lane = threadIdx.x & 63;
    int b = blockIdx.x * 4 + wave;
    int js = starts[b], je = starts[b + 1];
    float2 acc = {0.f, 0.f};
    for (int j = js; j < je; ++j) {
        int id = hist[j];
        float2 v = *(const float2*)(disc + (size_t)id * KDIM + 2 * lane);
        acc.x += v.x; acc.y += v.y;
    }
    float c = (float)(je - js); if (c < 1.f) c = 1.f;
    float2 r; r.x = acc.x / c; r.y = acc.y / c;
    *(float2*)(stu + (size_t)b * KDIM + 2 * lane) = r;
}

// ---------------------------------------------------------------- concept @ W[K:] vectors
__global__ __launch_bounds__(256) void cw_kernel(
    const float* __restrict__ full, const float* __restrict__ fsW,
    const float* __restrict__ feW, float* __restrict__ cw)
{
    int t = threadIdx.x;
    int j = t & 127;
    const float* w = (t < 128) ? (fsW + KDIM) : (feW + KDIM);
    const float* row = full + (size_t)j * KDIM;
    float s = 0.f;
    for (int k = 0; k < KDIM; ++k) s += row[k] * w[k];
    cw[t] = s;
}

// ---------------------------------------------------------------- fused head: 4 batch rows per block
__global__ __launch_bounds__(256) void final_kernel(
    const float* __restrict__ stu, const float* __restrict__ full,
    const float* __restrict__ cw,
    const float* __restrict__ fsW, const float* __restrict__ fsB,
    const float* __restrict__ feW, const float* __restrict__ feB,
    const float* __restrict__ disc_emb, const int* __restrict__ exer_id,
    const float* __restrict__ kn,
    const float* __restrict__ W1, const float* __restrict__ b1,
    const float* __restrict__ W2, const float* __restrict__ b2,
    const float* __restrict__ W3, const float* __restrict__ b3,
    float* __restrict__ out)
{
    __shared__ float xs[4][KDIM];
    __shared__ float o1s[4][512];
    __shared__ float o2s[4][216];
    int t = threadIdx.x, wave = t >> 6, lane = t & 63;
    int b = blockIdx.x * 4 + wave;
    int eid = exer_id[b];
    const float* sr = stu + (size_t)b * KDIM;
    const float* er = full + (size_t)(KDIM + eid) * KDIM;
    float sd = sr[lane] * fsW[lane] + sr[lane + 64] * fsW[lane + 64];
    float ed = er[lane] * feW[lane] + er[lane + 64] * feW[lane + 64];
    #pragma unroll
    for (int o = 32; o > 0; o >>= 1) {
        sd += __shfl_xor(sd, o);
        ed += __shfl_xor(ed, o);
    }
    float edisc = 10.f * sigmoidf(disc_emb[eid]);
    float fsb = fsB[0], feb = feB[0];
    for (int j = lane; j < KDIM; j += 64) {
        float prof = sigmoidf(sd + cw[j] + fsb);
        float diff = sigmoidf(ed + cw[KDIM + j] + feb);
        xs[wave][j] = edisc * (prof - diff) * kn[(size_t)b * KDIM + j];
    }
    __syncthreads();
    float acc[4][2] = {};
    for (int k = 0; k < KDIM; ++k) {
        float w0 = W1[k * 512 + t];
        float w1 = W1[k * 512 + t + 256];
        #pragma unroll
        for (int r = 0; r < 4; ++r) {
            float a = xs[r][k];
            acc[r][0] += a * w0;
            acc[r][1] += a * w1;
        }
    }
    #pragma unroll
    for (int r = 0; r < 4; ++r) {
        o1s[r][t] = sigmoidf(acc[r][0] + b1[t]);
        o1s[r][t + 256] = sigmoidf(acc[r][1] + b1[t + 256]);
    }
    __syncthreads();
    if (t < 216) {
        float acc2[4] = {};
        for (int k = 0; k < 512; ++k) {
            float w = W2[k * 216 + t];
            #pragma unroll
            for (int r = 0; r < 4; ++r) acc2[r] += o1s[r][k] * w;
        }
        #pragma unroll
        for (int r = 0; r < 4; ++r) o2s[r][t] = sigmoidf(acc2[r] + b2[t]);
    }
    __syncthreads();
    float dot = 0.f;
    for (int p = lane; p < 216; p += 64) dot += o2s[wave][p] * W3[p];
    #pragma unroll
    for (int o = 32; o > 0; o >>= 1) dot += __shfl_xor(dot, o);
    if (lane == 0) out[b] = sigmoidf(dot + b3[0]);
}

// ================================================================ host
extern "C" void kernel_launch(void* const* d_in, const int* in_sizes, int n_in,
                              void* d_out, int out_size, void* d_ws, size_t ws_size,
                              hipStream_t stream)
{
    (void)in_sizes; (void)n_in; (void)out_size; (void)ws_size;
    const float* entity = (const float*)d_in[0];
    const float* gcnW   = (const float*)d_in[1];
    const float* gcnB   = (const float*)d_in[2];
    const float* fsW    = (const float*)d_in[3];
    const float* fsB    = (const float*)d_in[4];
    const float* feW    = (const float*)d_in[5];
    const float* feB    = (const float*)d_in[6];
    const float* disc_emb = (const float*)d_in[7];
    const float* W1 = (const float*)d_in[8];
    const float* b1 = (const float*)d_in[9];
    const float* W2 = (const float*)d_in[10];
    const float* b2 = (const float*)d_in[11];
    const float* W3 = (const float*)d_in[12];
    const float* b3 = (const float*)d_in[13];
    const int* s0 = (const int*)d_in[14];
    const int* d0 = (const int*)d_in[15];
    const int* s1 = (const int*)d_in[16];
    const int* d1 = (const int*)d_in[17];
    const int* s2 = (const int*)d_in[18];
    const int* d2 = (const int*)d_in[19];
    const int* exer_id = (const int*)d_in[21];
    const float* kn = (const float*)d_in[22];
    const int* hist = (const int*)d_in[23];
    const int* segid = (const int*)d_in[24];
    float* out = (float*)d_out;

    char* wsb = (char*)d_ws;
    size_t off = 0;
    auto alloc = [&](size_t bytes) -> void* {
        void* p = wsb + off;
        off = (off + bytes + 255) & ~(size_t)255;
        return p;
    };
    int*   partial = (int*)alloc((size_t)6 * NCHUNK * NNODE * sizeof(int));  // 3.2 MB
    int*   cnt     = (int*)alloc((size_t)6 * NNODE * sizeof(int));
    int*   rp      = (int*)alloc((size_t)3 * (NNODE + 1) * sizeof(int));
    int*   chunk_base = (int*)alloc((size_t)3 * NCHUNK * NNODE * sizeof(int)); // 1.6 MB
    int*   csr_src = (int*)alloc((size_t)3 * NEDGE * sizeof(int));
    float* csr_w   = (float*)alloc((size_t)3 * NEDGE * sizeof(float));
    ushort* h_bf   = (ushort*)alloc((size_t)NNODE * KDIM * sizeof(ushort));
    ushort* agg    = (ushort*)alloc((size_t)3 * NNODE * KDIM * sizeof(ushort));
    ushort* Wt     = (ushort*)alloc((size_t)3 * 4 * KDIM * KDIM * sizeof(ushort));
    float* full_acc= (float*)alloc((size_t)NNODE * KDIM * sizeof(float));
    float* disc_acc= (float*)alloc((size_t)NEXER * KDIM * sizeof(float));
    float* stu     = (float*)alloc((size_t)NBATCH * KDIM * sizeof(float));
    int*   starts  = (int*)alloc((size_t)(NBATCH + 1) * sizeof(int));
    float* cw      = (float*)alloc(256 * sizeof(float));

    prep_emb_kernel<<<(NNODE * KDIM / 2 + 255) / 256, 256, 0, stream>>>(entity, h_bf, full_acc);
    prep_w_kernel<<<dim3(16, 12), 256, 0, stream>>>(gcnW, Wt);

    // atomic-free CSR build
    count_part_kernel<<<dim3(NCHUNK, 2, 6), 256, 0, stream>>>(s0, d0, s1, d1, s2, d2, partial);
    sum_kernel<<<(6 * NNODE + 255) / 256, 256, 0, stream>>>(partial, cnt);
    scan_kernel<<<3, 256, 0, stream>>>(cnt, rp);
    base_kernel<<<(3 * NNODE + 255) / 256, 256, 0, stream>>>(partial, rp, chunk_base);
    fill_part_kernel<<<dim3(NCHUNK, 2, 3), 256, 0, stream>>>(s0, d0, s1, d1, s2, d2,
                                                             cnt, chunk_base, csr_src, csr_w);

    for (int l = 0; l < 4; ++l) {
        gather_kernel<<<NNODE / 4, 256, 0, stream>>>(h_bf, csr_src, csr_w, rp, agg);
        gemm_kernel<<<NNODE / 64, 256, 0, stream>>>(agg, Wt, gcnB, l, h_bf, full_acc, disc_acc);
    }

    constexpr int SCALE_ELEMS = NNODE * KDIM / 4 + NEXER * KDIM / 4;
    scale_kernel<<<(SCALE_ELEMS + 255) / 256, 256, 0, stream>>>(full_acc, disc_acc);
    starts_kernel<<<(NBATCH + 1 + 255) / 256, 256, 0, stream>>>(segid, starts);
    stu_kernel<<<NBATCH / 4, 256, 0, stream>>>(disc_acc, hist, starts, stu);
    cw_kernel<<<1, 256, 0, stream>>>(full_acc, fsW, feW, cw);
    final_kernel<<<NBATCH / 4, 256, 0, stream>>>(stu, full_acc, cw, fsW, fsB, feW, feB,
                                                 disc_emb, exer_id, kn,
                                                 W1, b1, W2, b2, W3, b3, out);
}